// Round 6
// baseline (56.888 us; speedup 1.0000x reference)
//
#include <hip/hip_runtime.h>

typedef __attribute__((ext_vector_type(8))) __bf16 bf16x8;
typedef __attribute__((ext_vector_type(4))) float f32x4;
typedef __attribute__((ext_vector_type(4))) unsigned int u32x4;
typedef __attribute__((ext_vector_type(2))) unsigned int u32x2;

// LDS (exactly 80 KB -> 2 blocks/CU):
//   XQ: 128 local q-rows * 128B = 16 KB  (Q then P; wave-private rows)
//   K : 256 keys * 128B        = 32 KB
//   VT: 64 h * 512B            = 32 KB  (W staged here bf16 first, then V^T)
#define LDS_XQ 0
#define LDS_K  16384
#define LDS_VT 49152
#define LDS_TOT 81920
#define W_Q (LDS_VT)
#define W_K (LDS_VT + 8192)
#define W_V (LDS_VT + 16384)

static __device__ __forceinline__ unsigned int cvt_pk_bf16(float a, float b) {
  unsigned int r;
  asm("v_cvt_pk_bf16_f32 %0, %1, %2" : "=v"(r) : "v"(a), "v"(b));
  return r;
}
static __device__ __forceinline__ int swz128(int row, int colbyte) {
  return row * 128 + (colbyte ^ ((row & 7) << 4));
}
static __device__ __forceinline__ int swz512(int row, int colbyte) {
  return row * 512 + (colbyte ^ ((row & 7) << 4));
}
static __device__ __forceinline__ bf16x8 ldx(const float* p) {
  const float4* p4 = (const float4*)p;
  float4 lo = p4[0], hi = p4[1];
  u32x4 u;
  u.x = cvt_pk_bf16(lo.x, lo.y); u.y = cvt_pk_bf16(lo.z, lo.w);
  u.z = cvt_pk_bf16(hi.x, hi.y); u.w = cvt_pk_bf16(hi.z, hi.w);
  return __builtin_bit_cast(bf16x8, u);
}

// 2048 blocks: blockIdx>>1 = batch, blockIdx&1 = half (q-rows half*128..+128).
// 512 threads = 8 waves, each owns 16 q-rows + 1-2 key-tiles.
__global__ __launch_bounds__(512, 4)
void head_fused(const float* __restrict__ x,
                const float* __restrict__ Wq, const float* __restrict__ bq,
                const float* __restrict__ Wk, const float* __restrict__ bk,
                const float* __restrict__ Wv, const float* __restrict__ bv,
                float* __restrict__ out)
{
  __shared__ __align__(16) char smem[LDS_TOT];
  const int bid  = blockIdx.x;
  const int b    = bid >> 1;
  const int half = bid & 1;
  const int tid  = threadIdx.x;
  const int lane = tid & 63;
  const int wid  = tid >> 6;      // 8 waves
  const int g    = lane >> 4;
  const int ln   = lane & 15;

  const float* xb = x + (size_t)b * (256 * 64);

  // ---- X fragments direct global->regs (key-tile rows; q-tile aliases one) --
  bf16x8 xk0[2], xk1[2], xq[2];
#pragma unroll
  for (int ks = 0; ks < 2; ++ks)
    xk0[ks] = ldx(xb + (wid * 16 + ln) * 64 + ks * 32 + g * 8);
  if (half) {
#pragma unroll
    for (int ks = 0; ks < 2; ++ks) {
      xk1[ks] = ldx(xb + ((wid + 8) * 16 + ln) * 64 + ks * 32 + g * 8);
      xq[ks]  = xk1[ks];
    }
  } else {
#pragma unroll
    for (int ks = 0; ks < 2; ++ks) xq[ks] = xk0[ks];
  }

  // ---- stage W f32->bf16 into VT region (shared by the block) -------------
#pragma unroll
  for (int i = 0; i < 6; ++i) {
    int idx = tid + i * 512;               // 3072 float4 total
    int mat = idx >> 10;
    int rem = idx & 1023;
    const float4* wg = (const float4*)(mat == 0 ? Wq : (mat == 1 ? Wk : Wv));
    float4 v = wg[rem];
    int e = rem * 4;
    int h = e >> 6, c = e & 63;
    u32x2 p;
    p.x = cvt_pk_bf16(v.x, v.y);
    p.y = cvt_pk_bf16(v.z, v.w);
    *(u32x2*)(smem + W_Q + mat * 8192 + swz128(h, c * 2)) = p;
  }
  __syncthreads();

  // ---- Phase 1a: Q-proj + K-proj (read W LDS), Wv -> regs -----------------
  // Q = Wq·Xq^T: D[h][q] -> store row-major Q[q][h] in XQ (local rows).
#pragma unroll
  for (int mt = 0; mt < 4; ++mt) {
    float4 bb = *(const float4*)(bq + mt * 16 + g * 4);
    f32x4 acc = {0.f, 0.f, 0.f, 0.f};
#pragma unroll
    for (int ks = 0; ks < 2; ++ks) {
      u32x4 u = *(const u32x4*)(smem + W_Q + swz128(mt * 16 + ln, (ks * 32 + g * 8) * 2));
      acc = __builtin_amdgcn_mfma_f32_16x16x32_bf16(
              __builtin_bit_cast(bf16x8, u), xq[ks], acc, 0, 0, 0);
    }
    u32x2 p;
    p.x = cvt_pk_bf16((acc[0] + bb.x) * 0.125f, (acc[1] + bb.y) * 0.125f);
    p.y = cvt_pk_bf16((acc[2] + bb.z) * 0.125f, (acc[3] + bb.w) * 0.125f);
    *(u32x2*)(smem + LDS_XQ + swz128(wid * 16 + ln, (mt * 16 + g * 4) * 2)) = p;
  }
  // K = Wk·Xk^T for key-tile(s): store K[key][h].
#pragma unroll
  for (int mt = 0; mt < 4; ++mt) {
    float4 bb = *(const float4*)(bk + mt * 16 + g * 4);
    f32x4 acc = {0.f, 0.f, 0.f, 0.f};
#pragma unroll
    for (int ks = 0; ks < 2; ++ks) {
      u32x4 u = *(const u32x4*)(smem + W_K + swz128(mt * 16 + ln, (ks * 32 + g * 8) * 2));
      acc = __builtin_amdgcn_mfma_f32_16x16x32_bf16(
              __builtin_bit_cast(bf16x8, u), xk0[ks], acc, 0, 0, 0);
    }
    u32x2 p;
    p.x = cvt_pk_bf16(acc[0] + bb.x, acc[1] + bb.y);
    p.y = cvt_pk_bf16(acc[2] + bb.z, acc[3] + bb.w);
    *(u32x2*)(smem + LDS_K + swz128(wid * 16 + ln, (mt * 16 + g * 4) * 2)) = p;
  }
  if (half) {
#pragma unroll
    for (int mt = 0; mt < 4; ++mt) {
      float4 bb = *(const float4*)(bk + mt * 16 + g * 4);
      f32x4 acc = {0.f, 0.f, 0.f, 0.f};
#pragma unroll
      for (int ks = 0; ks < 2; ++ks) {
        u32x4 u = *(const u32x4*)(smem + W_K + swz128(mt * 16 + ln, (ks * 32 + g * 8) * 2));
        acc = __builtin_amdgcn_mfma_f32_16x16x32_bf16(
                __builtin_bit_cast(bf16x8, u), xk1[ks], acc, 0, 0, 0);
      }
      u32x2 p;
      p.x = cvt_pk_bf16(acc[0] + bb.x, acc[1] + bb.y);
      p.y = cvt_pk_bf16(acc[2] + bb.z, acc[3] + bb.w);
      *(u32x2*)(smem + LDS_K + swz128((wid + 8) * 16 + ln, (mt * 16 + g * 4) * 2)) = p;
    }
  }
  // Wv fragments + bv to registers (W region dies at next barrier).
  bf16x8 wv[4][2];
  float bvv[4];
#pragma unroll
  for (int nf = 0; nf < 4; ++nf) {
    bvv[nf] = bv[nf * 16 + ln];
#pragma unroll
    for (int ks = 0; ks < 2; ++ks) {
      u32x4 u = *(const u32x4*)(smem + W_V + swz128(nf * 16 + ln, (ks * 32 + g * 8) * 2));
      wv[nf][ks] = __builtin_bit_cast(bf16x8, u);
    }
  }
  __syncthreads();

  // ---- Phase 1b: V-proj -> VT (overwrites W region) -----------------------
#pragma unroll
  for (int nf = 0; nf < 4; ++nf) {
    f32x4 acc = {0.f, 0.f, 0.f, 0.f};
#pragma unroll
    for (int ks = 0; ks < 2; ++ks)
      acc = __builtin_amdgcn_mfma_f32_16x16x32_bf16(xk0[ks], wv[nf][ks], acc, 0, 0, 0);
    int t0 = wid * 16 + g * 4;
    u32x2 p;
    p.x = cvt_pk_bf16(acc[0] + bvv[nf], acc[1] + bvv[nf]);
    p.y = cvt_pk_bf16(acc[2] + bvv[nf], acc[3] + bvv[nf]);
    *(u32x2*)(smem + LDS_VT + swz512(nf * 16 + ln, t0 * 2)) = p;
  }
  if (half) {
#pragma unroll
    for (int nf = 0; nf < 4; ++nf) {
      f32x4 acc = {0.f, 0.f, 0.f, 0.f};
#pragma unroll
      for (int ks = 0; ks < 2; ++ks)
        acc = __builtin_amdgcn_mfma_f32_16x16x32_bf16(xk1[ks], wv[nf][ks], acc, 0, 0, 0);
      int t0 = (wid + 8) * 16 + g * 4;
      u32x2 p;
      p.x = cvt_pk_bf16(acc[0] + bvv[nf], acc[1] + bvv[nf]);
      p.y = cvt_pk_bf16(acc[2] + bvv[nf], acc[3] + bvv[nf]);
      *(u32x2*)(smem + LDS_VT + swz512(nf * 16 + ln, t0 * 2)) = p;
    }
  }
  __syncthreads();

  // ---- Phase 2: flash attention (wave owns local q rows [16w,16w+16)) -----
  bf16x8 qa[2];
#pragma unroll
  for (int ks = 0; ks < 2; ++ks) {
    u32x4 u = *(const u32x4*)(smem + LDS_XQ + swz128(wid * 16 + ln, (ks * 32 + g * 8) * 2));
    qa[ks] = __builtin_bit_cast(bf16x8, u);
  }

  float mrun = -1e30f, lrun = 0.f;
  f32x4 oacc[4];
#pragma unroll
  for (int nf = 0; nf < 4; ++nf)
    oacc[nf] = (f32x4){0.f, 0.f, 0.f, 0.f};

  const int qtile = half * 128 + wid * 16;     // global q-row base
  const int jmax = qtile >> 6;
  for (int jt = 0; jt <= jmax; ++jt) {
    f32x4 s[4];
#pragma unroll
    for (int nk = 0; nk < 4; ++nk)
      s[nk] = (f32x4){0.f, 0.f, 0.f, 0.f};
#pragma unroll
    for (int ks = 0; ks < 2; ++ks) {
      bf16x8 kb[4];
#pragma unroll
      for (int nk = 0; nk < 4; ++nk) {
        int key = jt * 64 + nk * 16 + ln;
        u32x4 u = *(const u32x4*)(smem + LDS_K + swz128(key, (ks * 32 + g * 8) * 2));
        kb[nk] = __builtin_bit_cast(bf16x8, u);
      }
#pragma unroll
      for (int nk = 0; nk < 4; ++nk)
        s[nk] = __builtin_amdgcn_mfma_f32_16x16x32_bf16(kb[nk], qa[ks], s[nk], 0, 0, 0);
    }
    if (jt == jmax) {
      int q_abs = qtile + ln;
#pragma unroll
      for (int nk = 0; nk < 4; ++nk) {
        int keybase = jt * 64 + nk * 16 + g * 4;
#pragma unroll
        for (int d = 0; d < 4; ++d)
          s[nk][d] = (keybase + d > q_abs) ? -1e30f : s[nk][d];
      }
    }
    {
      f32x4 m4;
#pragma unroll
      for (int d = 0; d < 4; ++d)
        m4[d] = fmaxf(fmaxf(s[0][d], s[1][d]), fmaxf(s[2][d], s[3][d]));
      float mx = fmaxf(fmaxf(m4[0], m4[1]), fmaxf(m4[2], m4[3]));
      mx = fmaxf(mx, __shfl_xor(mx, 16));
      mx = fmaxf(mx, __shfl_xor(mx, 32));
      float mn = fmaxf(mrun, mx);
      float a  = __expf(mrun - mn);
      mrun = mn;
      float sum = 0.f;
#pragma unroll
      for (int nk = 0; nk < 4; ++nk)
#pragma unroll
        for (int d = 0; d < 4; ++d) {
          float p = __expf(s[nk][d] - mn);
          s[nk][d] = p;
          sum += p;
        }
      sum += __shfl_xor(sum, 16);
      sum += __shfl_xor(sum, 32);
      lrun = lrun * a + sum;
#pragma unroll
      for (int d = 0; d < 4; ++d) {
        float ad = __shfl(a, g * 4 + d);
#pragma unroll
        for (int nf = 0; nf < 4; ++nf)
          oacc[nf][d] *= ad;
      }
#pragma unroll
      for (int nk = 0; nk < 4; ++nk) {
        u32x2 p;
        p.x = cvt_pk_bf16(s[nk][0], s[nk][1]);
        p.y = cvt_pk_bf16(s[nk][2], s[nk][3]);
        *(u32x2*)(smem + LDS_XQ + swz128(wid * 16 + ln, (nk * 16 + g * 4) * 2)) = p;
      }
    }
#pragma unroll
    for (int ks = 0; ks < 2; ++ks) {
      bf16x8 pa;
      {
        u32x4 u = *(const u32x4*)(smem + LDS_XQ + swz128(wid * 16 + ln, (ks * 32 + g * 8) * 2));
        pa = __builtin_bit_cast(bf16x8, u);
      }
      bf16x8 vb[4];
#pragma unroll
      for (int nf = 0; nf < 4; ++nf) {
        int key0 = jt * 64 + ks * 32 + g * 8;
        u32x4 u = *(const u32x4*)(smem + LDS_VT + swz512(nf * 16 + ln, key0 * 2));
        vb[nf] = __builtin_bit_cast(bf16x8, u);
      }
#pragma unroll
      for (int nf = 0; nf < 4; ++nf)
        oacc[nf] = __builtin_amdgcn_mfma_f32_16x16x32_bf16(pa, vb[nf], oacc[nf], 0, 0, 0);
    }
  }

  // ---- Epilogue ----
  float* og = out + (size_t)b * (256 * 64);
  {
    float linv = 1.0f / lrun;
    float inv[4];
#pragma unroll
    for (int d = 0; d < 4; ++d) inv[d] = __shfl(linv, g * 4 + d);
#pragma unroll
    for (int nf = 0; nf < 4; ++nf)
#pragma unroll
      for (int d = 0; d < 4; ++d) {
        int t = qtile + g * 4 + d;
        og[t * 64 + nf * 16 + ln] = oacc[nf][d] * inv[d];
      }
  }
}

extern "C" void kernel_launch(void* const* d_in, const int* in_sizes, int n_in,
                              void* d_out, int out_size, void* d_ws, size_t ws_size,
                              hipStream_t stream) {
  (void)in_sizes; (void)n_in; (void)d_ws; (void)ws_size; (void)out_size;
  const float* x  = (const float*)d_in[0];
  const float* Wq = (const float*)d_in[1];
  const float* bq = (const float*)d_in[2];
  const float* Wk = (const float*)d_in[3];
  const float* bk = (const float*)d_in[4];
  const float* Wv = (const float*)d_in[5];
  const float* bv = (const float*)d_in[6];
  float* out = (float*)d_out;
  hipLaunchKernelGGL(head_fused, dim3(2048), dim3(512), 0, stream,
                     x, Wq, bq, Wk, bk, Wv, bv, out);
}

// Round 7
// 41.169 us; speedup vs baseline: 1.3818x; 1.3818x over previous
//
#include <hip/hip_runtime.h>

typedef __attribute__((ext_vector_type(8))) __bf16 bf16x8;
typedef __attribute__((ext_vector_type(4))) float f32x4;
typedef __attribute__((ext_vector_type(4))) unsigned int u32x4;
typedef __attribute__((ext_vector_type(2))) unsigned int u32x2;

// LDS 74 KB -> 2 blocks/CU (2x75776 = 151552 < 163840, with margin):
//   SCR: 8 waves * 16 rows * 80B = 10240  (wave-private Q/P transpose scratch)
//   K  : 256 keys * 128B         = 32768
//   VT : 64 h * 512B             = 32768  (W staged bf16 here first, then V^T)
#define LDS_SCR 0
#define LDS_K   10240
#define LDS_VT  43008
#define LDS_TOT 75776
#define W_Q (LDS_VT)
#define W_K (LDS_VT + 8192)
#define W_V (LDS_VT + 16384)

static __device__ __forceinline__ unsigned int cvt_pk_bf16(float a, float b) {
  unsigned int r;
  asm("v_cvt_pk_bf16_f32 %0, %1, %2" : "=v"(r) : "v"(a), "v"(b));
  return r;
}
static __device__ __forceinline__ int swz128(int row, int colbyte) {
  return row * 128 + (colbyte ^ ((row & 7) << 4));
}
static __device__ __forceinline__ int swz512(int row, int colbyte) {
  return row * 512 + (colbyte ^ ((row & 7) << 4));
}
static __device__ __forceinline__ bf16x8 ldx(const float* p) {
  const float4* p4 = (const float4*)p;
  float4 lo = p4[0], hi = p4[1];
  u32x4 u;
  u.x = cvt_pk_bf16(lo.x, lo.y); u.y = cvt_pk_bf16(lo.z, lo.w);
  u.z = cvt_pk_bf16(hi.x, hi.y); u.w = cvt_pk_bf16(hi.z, hi.w);
  return __builtin_bit_cast(bf16x8, u);
}

// 1024 blocks (1/batch), 512 threads = 8 waves.
// Wave w owns q/key tile pair {w, 15-w}: causal work = 5 jt-units for every
// wave (balanced), processed sequentially through wave-private scratch.
__global__ __launch_bounds__(512, 4)
void head_fused(const float* __restrict__ x,
                const float* __restrict__ Wq, const float* __restrict__ bq,
                const float* __restrict__ Wk, const float* __restrict__ bk,
                const float* __restrict__ Wv, const float* __restrict__ bv,
                float* __restrict__ out)
{
  __shared__ __align__(16) char smem[LDS_TOT];
  const int b    = blockIdx.x;
  const int tid  = threadIdx.x;
  const int lane = tid & 63;
  const int wid  = tid >> 6;      // 8 waves
  const int g    = lane >> 4;
  const int ln   = lane & 15;
  const int tA   = wid;           // tile pair (balanced causal load)
  const int tB   = 15 - wid;

  const float* xb = x + (size_t)b * (256 * 64);
  char* scr = smem + LDS_SCR + wid * 1280;   // 16 rows * 80B, wave-private

  // ---- X fragments for both tiles, direct global->regs -------------------
  bf16x8 xfA[2], xfB[2];
#pragma unroll
  for (int ks = 0; ks < 2; ++ks) {
    xfA[ks] = ldx(xb + (tA * 16 + ln) * 64 + ks * 32 + g * 8);
    xfB[ks] = ldx(xb + (tB * 16 + ln) * 64 + ks * 32 + g * 8);
  }

  // ---- stage W f32->bf16 into VT region (shared) --------------------------
#pragma unroll
  for (int i = 0; i < 6; ++i) {
    int idx = tid + i * 512;               // 3072 float4 total
    int mat = idx >> 10;
    int rem = idx & 1023;
    const float4* wg = (const float4*)(mat == 0 ? Wq : (mat == 1 ? Wk : Wv));
    float4 v = wg[rem];
    int e = rem * 4;
    int h = e >> 6, c = e & 63;
    u32x2 p;
    p.x = cvt_pk_bf16(v.x, v.y);
    p.y = cvt_pk_bf16(v.z, v.w);
    *(u32x2*)(smem + W_Q + mat * 8192 + swz128(h, c * 2)) = p;
  }
  __syncthreads();

  // ---- Q-proj (both tiles) -> qa regs via scratch transpose ---------------
  bf16x8 qaA[2], qaB[2];
#pragma unroll
  for (int ti = 0; ti < 2; ++ti) {
    bf16x8 xf0 = ti ? xfB[0] : xfA[0];
    bf16x8 xf1 = ti ? xfB[1] : xfA[1];
#pragma unroll
    for (int hk = 0; hk < 2; ++hk) {
#pragma unroll
      for (int mt2 = 0; mt2 < 2; ++mt2) {
        int mt = hk * 2 + mt2;
        float4 bb = *(const float4*)(bq + mt * 16 + g * 4);
        f32x4 acc = {0.f, 0.f, 0.f, 0.f};
        {
          u32x4 u = *(const u32x4*)(smem + W_Q + swz128(mt * 16 + ln, (0 * 32 + g * 8) * 2));
          acc = __builtin_amdgcn_mfma_f32_16x16x32_bf16(__builtin_bit_cast(bf16x8, u), xf0, acc, 0, 0, 0);
        }
        {
          u32x4 u = *(const u32x4*)(smem + W_Q + swz128(mt * 16 + ln, (1 * 32 + g * 8) * 2));
          acc = __builtin_amdgcn_mfma_f32_16x16x32_bf16(__builtin_bit_cast(bf16x8, u), xf1, acc, 0, 0, 0);
        }
        u32x2 p;
        p.x = cvt_pk_bf16((acc[0] + bb.x) * 0.125f, (acc[1] + bb.y) * 0.125f);
        p.y = cvt_pk_bf16((acc[2] + bb.z) * 0.125f, (acc[3] + bb.w) * 0.125f);
        *(u32x2*)(scr + ln * 80 + mt2 * 32 + g * 8) = p;   // D[h][q] -> row q
      }
      u32x4 u = *(const u32x4*)(scr + ln * 80 + g * 16);   // A-frag [q][h-half]
      if (ti) qaB[hk] = __builtin_bit_cast(bf16x8, u);
      else    qaA[hk] = __builtin_bit_cast(bf16x8, u);
    }
  }

  // ---- K-proj (both tiles) -> K region ------------------------------------
#pragma unroll
  for (int ti = 0; ti < 2; ++ti) {
    int tile = ti ? tB : tA;
    bf16x8 xf0 = ti ? xfB[0] : xfA[0];
    bf16x8 xf1 = ti ? xfB[1] : xfA[1];
#pragma unroll
    for (int mt = 0; mt < 4; ++mt) {
      float4 bb = *(const float4*)(bk + mt * 16 + g * 4);
      f32x4 acc = {0.f, 0.f, 0.f, 0.f};
      {
        u32x4 u = *(const u32x4*)(smem + W_K + swz128(mt * 16 + ln, (0 * 32 + g * 8) * 2));
        acc = __builtin_amdgcn_mfma_f32_16x16x32_bf16(__builtin_bit_cast(bf16x8, u), xf0, acc, 0, 0, 0);
      }
      {
        u32x4 u = *(const u32x4*)(smem + W_K + swz128(mt * 16 + ln, (1 * 32 + g * 8) * 2));
        acc = __builtin_amdgcn_mfma_f32_16x16x32_bf16(__builtin_bit_cast(bf16x8, u), xf1, acc, 0, 0, 0);
      }
      u32x2 p;
      p.x = cvt_pk_bf16(acc[0] + bb.x, acc[1] + bb.y);
      p.y = cvt_pk_bf16(acc[2] + bb.z, acc[3] + bb.w);
      *(u32x2*)(smem + LDS_K + swz128(tile * 16 + ln, (mt * 16 + g * 4) * 2)) = p;
    }
  }

  // ---- Wv fragments + bv to registers (W region dies at next barrier) -----
  bf16x8 wv[4][2];
  float bvv[4];
#pragma unroll
  for (int nf = 0; nf < 4; ++nf) {
    bvv[nf] = bv[nf * 16 + ln];
#pragma unroll
    for (int ks = 0; ks < 2; ++ks) {
      u32x4 u = *(const u32x4*)(smem + W_V + swz128(nf * 16 + ln, (ks * 32 + g * 8) * 2));
      wv[nf][ks] = __builtin_bit_cast(bf16x8, u);
    }
  }
  __syncthreads();

  // ---- V-proj (both tiles) -> VT (overwrites W region) --------------------
#pragma unroll
  for (int ti = 0; ti < 2; ++ti) {
    int tile = ti ? tB : tA;
    bf16x8 xf0 = ti ? xfB[0] : xfA[0];
    bf16x8 xf1 = ti ? xfB[1] : xfA[1];
#pragma unroll
    for (int nf = 0; nf < 4; ++nf) {
      f32x4 acc = {0.f, 0.f, 0.f, 0.f};
      acc = __builtin_amdgcn_mfma_f32_16x16x32_bf16(xf0, wv[nf][0], acc, 0, 0, 0);
      acc = __builtin_amdgcn_mfma_f32_16x16x32_bf16(xf1, wv[nf][1], acc, 0, 0, 0);
      int t0 = tile * 16 + g * 4;
      u32x2 p;
      p.x = cvt_pk_bf16(acc[0] + bvv[nf], acc[1] + bvv[nf]);
      p.y = cvt_pk_bf16(acc[2] + bvv[nf], acc[3] + bvv[nf]);
      *(u32x2*)(smem + LDS_VT + swz512(nf * 16 + ln, t0 * 2)) = p;
    }
  }
  __syncthreads();

  // ---- Flash attention: tiles A then B (wave-private, no barriers) --------
  float* og = out + (size_t)b * (256 * 64);
#pragma unroll
  for (int ti = 0; ti < 2; ++ti) {
    const int tile = ti ? tB : tA;
    bf16x8 qa0 = ti ? qaB[0] : qaA[0];
    bf16x8 qa1 = ti ? qaB[1] : qaA[1];
    const int qbase = tile * 16;
    const int jmaxT = qbase >> 6;

    float mrun = -1e30f, lrun = 0.f;
    f32x4 oacc[4];
#pragma unroll
    for (int nf = 0; nf < 4; ++nf)
      oacc[nf] = (f32x4){0.f, 0.f, 0.f, 0.f};

    for (int jt = 0; jt <= jmaxT; ++jt) {
      // S = K·Q^T: s[nk][d] = S[key=jt*64+nk*16+g*4+d][q=qbase+ln]
      f32x4 s[4];
#pragma unroll
      for (int nk = 0; nk < 4; ++nk)
        s[nk] = (f32x4){0.f, 0.f, 0.f, 0.f};
#pragma unroll
      for (int ks = 0; ks < 2; ++ks) {
        bf16x8 qk = ks ? qa1 : qa0;
        bf16x8 kb[4];
#pragma unroll
        for (int nk = 0; nk < 4; ++nk) {
          int key = jt * 64 + nk * 16 + ln;
          u32x4 u = *(const u32x4*)(smem + LDS_K + swz128(key, (ks * 32 + g * 8) * 2));
          kb[nk] = __builtin_bit_cast(bf16x8, u);
        }
#pragma unroll
        for (int nk = 0; nk < 4; ++nk)
          s[nk] = __builtin_amdgcn_mfma_f32_16x16x32_bf16(kb[nk], qk, s[nk], 0, 0, 0);
      }
      if (jt == jmaxT) {
        int q_abs = qbase + ln;
#pragma unroll
        for (int nk = 0; nk < 4; ++nk) {
          int keybase = jt * 64 + nk * 16 + g * 4;
#pragma unroll
          for (int d = 0; d < 4; ++d)
            s[nk][d] = (keybase + d > q_abs) ? -1e30f : s[nk][d];
        }
      }
      // online softmax (lane owns q-row)
      {
        f32x4 m4;
#pragma unroll
        for (int d = 0; d < 4; ++d)
          m4[d] = fmaxf(fmaxf(s[0][d], s[1][d]), fmaxf(s[2][d], s[3][d]));
        float mx = fmaxf(fmaxf(m4[0], m4[1]), fmaxf(m4[2], m4[3]));
        mx = fmaxf(mx, __shfl_xor(mx, 16));
        mx = fmaxf(mx, __shfl_xor(mx, 32));
        float mn = fmaxf(mrun, mx);
        float a  = __expf(mrun - mn);
        mrun = mn;
        float sum = 0.f;
#pragma unroll
        for (int nk = 0; nk < 4; ++nk)
#pragma unroll
          for (int d = 0; d < 4; ++d) {
            float p = __expf(s[nk][d] - mn);
            s[nk][d] = p;
            sum += p;
          }
        sum += __shfl_xor(sum, 16);
        sum += __shfl_xor(sum, 32);
        lrun = lrun * a + sum;
#pragma unroll
        for (int d = 0; d < 4; ++d) {
          float ad = __shfl(a, g * 4 + d);
#pragma unroll
          for (int nf = 0; nf < 4; ++nf)
            oacc[nf][d] *= ad;
        }
      }
      // P -> scratch in 32-key halves, PV per half
#pragma unroll
      for (int h2 = 0; h2 < 2; ++h2) {
#pragma unroll
        for (int n2 = 0; n2 < 2; ++n2) {
          f32x4 sv = s[h2 * 2 + n2];
          u32x2 p;
          p.x = cvt_pk_bf16(sv[0], sv[1]);
          p.y = cvt_pk_bf16(sv[2], sv[3]);
          *(u32x2*)(scr + ln * 80 + n2 * 32 + g * 8) = p;
        }
        bf16x8 pa;
        {
          u32x4 u = *(const u32x4*)(scr + ln * 80 + g * 16);
          pa = __builtin_bit_cast(bf16x8, u);
        }
        bf16x8 vb[4];
#pragma unroll
        for (int nf = 0; nf < 4; ++nf) {
          int key0 = jt * 64 + h2 * 32 + g * 8;
          u32x4 u = *(const u32x4*)(smem + LDS_VT + swz512(nf * 16 + ln, key0 * 2));
          vb[nf] = __builtin_bit_cast(bf16x8, u);
        }
#pragma unroll
        for (int nf = 0; nf < 4; ++nf)
          oacc[nf] = __builtin_amdgcn_mfma_f32_16x16x32_bf16(pa, vb[nf], oacc[nf], 0, 0, 0);
      }
    }

    // epilogue for this tile
    {
      float linv = 1.0f / lrun;
      float inv[4];
#pragma unroll
      for (int d = 0; d < 4; ++d) inv[d] = __shfl(linv, g * 4 + d);
#pragma unroll
      for (int nf = 0; nf < 4; ++nf)
#pragma unroll
        for (int d = 0; d < 4; ++d) {
          int t = qbase + g * 4 + d;
          og[t * 64 + nf * 16 + ln] = oacc[nf][d] * inv[d];
        }
    }
  }
}

extern "C" void kernel_launch(void* const* d_in, const int* in_sizes, int n_in,
                              void* d_out, int out_size, void* d_ws, size_t ws_size,
                              hipStream_t stream) {
  (void)in_sizes; (void)n_in; (void)d_ws; (void)ws_size; (void)out_size;
  const float* x  = (const float*)d_in[0];
  const float* Wq = (const float*)d_in[1];
  const float* bq = (const float*)d_in[2];
  const float* Wk = (const float*)d_in[3];
  const float* bk = (const float*)d_in[4];
  const float* Wv = (const float*)d_in[5];
  const float* bv = (const float*)d_in[6];
  float* out = (float*)d_out;
  hipLaunchKernelGGL(head_fused, dim3(1024), dim3(512), 0, stream,
                     x, Wq, bq, Wk, bk, Wv, bv, out);
}